// Round 3
// baseline (1517.983 us; speedup 1.0000x reference)
//
#include <hip/hip_runtime.h>
#include <hip/hip_bf16.h>
#include <cstddef>

#define NN 200000   // nodes
#define NE 400000   // edges
#define DD 128      // embed dim
#define NL 5        // layers
#define NG 1000     // graphs
#define BOND_V 5
#define BM2 64            // rows per fused block
#define NBLK2 (NN / BM2)  // 3125
#define CHUNK 200         // pool chunk
#define NB_SCAN 200
#define CH 1000
#define EPS 1e-5f
#define XS 136            // LDS bf16 row stride (shorts): 272B = 68 dwords -> 2-way only

typedef __bf16 bf16x8 __attribute__((ext_vector_type(8)));
typedef float floatx4 __attribute__((ext_vector_type(4)));

__device__ __forceinline__ unsigned short f2bf(float f) {
    unsigned int u = __float_as_uint(f);
    u = (u + 0x7fffu + ((u >> 16) & 1u)) >> 16;
    return (unsigned short)u;
}
__device__ __forceinline__ float bf2f(unsigned short s) {
    return __uint_as_float(((unsigned int)s) << 16);
}

// ---------------- degree / counts ----------------
__global__ void k_deg_int(const int* __restrict__ dst, int* __restrict__ cnt) {
    int e = blockIdx.x * blockDim.x + threadIdx.x;
    if (e < NE) atomicAdd(&cnt[dst[e]], 1);
}

__global__ void k_cnt(const int* __restrict__ n2g, float* __restrict__ gcnt) {
    int n = blockIdx.x * blockDim.x + threadIdx.x;
    if (n < NN) atomicAdd(&gcnt[n2g[n]], 1.0f);
}

__global__ void k_rdeg(const int* __restrict__ cnt, float* __restrict__ rdeg) {
    int n = blockIdx.x * blockDim.x + threadIdx.x;
    if (n < NN) rdeg[n] = 1.0f / (float)(cnt[n] + 1);
}

// ---------------- CSR build ----------------
__global__ void k_scan1(const int* __restrict__ cnt, int* __restrict__ bsum) {
    __shared__ int sh[256];
    int b = blockIdx.x, t = threadIdx.x;
    int s = 0;
    if (t < CH / 4) {
        int base = b * CH + t * 4;
        s = cnt[base] + cnt[base + 1] + cnt[base + 2] + cnt[base + 3];
    }
    sh[t] = s;
    __syncthreads();
    if (t == 0) {
        int tot = 0;
        for (int i = 0; i < CH / 4; i++) tot += sh[i];
        bsum[b] = tot;
    }
}

__global__ void k_scan2(const int* __restrict__ bsum, int* __restrict__ bpre,
                        int* __restrict__ off) {
    if (threadIdx.x == 0) {
        int run = 0;
        for (int i = 0; i < NB_SCAN; i++) { bpre[i] = run; run += bsum[i]; }
        off[NN] = NE;
    }
}

__global__ void k_scan3(const int* __restrict__ cnt, const int* __restrict__ bpre,
                        int* __restrict__ off, int* __restrict__ cur) {
    __shared__ int sh[256];
    int b = blockIdx.x, t = threadIdx.x;
    int base = b * CH + t * 4;
    int c0 = 0, c1 = 0, c2 = 0, c3 = 0, s = 0;
    if (t < CH / 4) {
        c0 = cnt[base]; c1 = cnt[base + 1]; c2 = cnt[base + 2]; c3 = cnt[base + 3];
        s = c0 + c1 + c2 + c3;
    }
    sh[t] = s;
    __syncthreads();
    if (t == 0) {
        int run = bpre[b];
        for (int i = 0; i < CH / 4; i++) { int v = sh[i]; sh[i] = run; run += v; }
    }
    __syncthreads();
    if (t < CH / 4) {
        int run = sh[t];
        off[base] = run; cur[base] = run; run += c0;
        off[base + 1] = run; cur[base + 1] = run; run += c1;
        off[base + 2] = run; cur[base + 2] = run; run += c2;
        off[base + 3] = run; cur[base + 3] = run;
    }
}

__global__ void k_bucket(const int* __restrict__ src, const int* __restrict__ dst,
                         const int* __restrict__ efeat, int* __restrict__ cur,
                         int* __restrict__ esrc, int* __restrict__ eft) {
    int e = blockIdx.x * blockDim.x + threadIdx.x;
    if (e < NE) {
        int p = atomicAdd(&cur[dst[e]], 1);
        esrc[p] = src[e];
        eft[p] = efeat[e];
    }
}

// ---------------- W split: fp32 [l][k][n] -> bf16 hi/lo transposed [l][n][k] ----------------
__global__ void k_wsplit(const float* __restrict__ W, unsigned short* __restrict__ Wht,
                         unsigned short* __restrict__ Wlt) {
    int idx = blockIdx.x * 256 + threadIdx.x;
    if (idx >= NL * DD * DD) return;
    int l = idx / (DD * DD), rem = idx % (DD * DD);
    int k = rem / DD, n = rem % DD;
    float v = W[idx];
    unsigned short hb = f2bf(v);
    unsigned short lb = f2bf(v - bf2f(hb));
    size_t o = (size_t)l * DD * DD + (size_t)n * DD + k;
    Wht[o] = hb; Wlt[o] = lb;
}

// ---------------- fused BN+ReLU helper ----------------
__device__ __forceinline__ float4 bnrelu4(float4 x, float4 m, float4 r, float4 g, float4 b) {
    float4 o;
    o.x = fmaxf(0.f, (x.x - m.x) * r.x * g.x + b.x);
    o.y = fmaxf(0.f, (x.y - m.y) * r.y * g.y + b.y);
    o.z = fmaxf(0.f, (x.z - m.z) * r.z * g.z + b.z);
    o.w = fmaxf(0.f, (x.w - m.w) * r.w * g.w + b.w);
    return o;
}

// ---------------- fused layer: agg (CSR gather + prev BN/ReLU + deg norm)
// -> LDS bf16 hi/lo -> split MFMA GEMM -> bias -> C, BN-stat partials ----------------
__global__ __launch_bounds__(256)
void k_fused(const float* __restrict__ base, const int* __restrict__ nfeat, int first,
             const int* __restrict__ off, const int* __restrict__ esrc,
             const int* __restrict__ eft, const float* __restrict__ eemb,
             const float* __restrict__ rdeg,
             const float* __restrict__ mu, const float* __restrict__ rsig,
             const float* __restrict__ gamma, const float* __restrict__ beta,
             const unsigned short* __restrict__ Wht, const unsigned short* __restrict__ Wlt,
             const float* __restrict__ bias,
             float* __restrict__ C, float* __restrict__ part) {
    __shared__ unsigned short Xh[BM2 * XS];   // 17408 B
    __shared__ unsigned short Xl[BM2 * XS];   // 17408 B
    __shared__ float eS[BOND_V * DD];         // 2560 B
    __shared__ float red[8 * DD];             // 4096 B: [4][128] sums + [4][128] sumsq

    int tid = threadIdx.x;
    if (tid < BOND_V * DD / 4)
        *(float4*)(eS + tid * 4) = *(const float4*)(eemb + tid * 4);

    int lane32 = tid & 31, grp = tid >> 5;
    int n0 = blockIdx.x * BM2;
    int c4 = lane32 << 2;
    float4 m4, r4, g4, b4;
    if (!first) {
        m4 = *(const float4*)(mu + c4);
        r4 = *(const float4*)(rsig + c4);
        g4 = *(const float4*)(gamma + c4);
        b4 = *(const float4*)(beta + c4);
    }
    __syncthreads();

    // ---- aggregation phase: 8 groups x 8 nodes ----
    for (int i = 0; i < 8; i++) {
        int r = grp * 8 + i;
        int n = n0 + r;
        int rown = first ? nfeat[n] : n;
        float4 acc = *(const float4*)(base + (size_t)rown * DD + c4);
        if (!first) acc = bnrelu4(acc, m4, r4, g4, b4);
        int e0 = off[n], e1 = off[n + 1];
        for (int k = e0; k < e1; k++) {
            int s = esrc[k];
            int rowe = first ? nfeat[s] : s;
            float4 hv = *(const float4*)(base + (size_t)rowe * DD + c4);
            if (!first) hv = bnrelu4(hv, m4, r4, g4, b4);
            float4 ev = *(const float4*)(eS + eft[k] * DD + c4);
            acc.x += hv.x + ev.x;
            acc.y += hv.y + ev.y;
            acc.z += hv.z + ev.z;
            acc.w += hv.w + ev.w;
        }
        float rd = rdeg[n];
        acc.x *= rd; acc.y *= rd; acc.z *= rd; acc.w *= rd;
        // split to bf16 hi/lo and store to LDS
        unsigned short h0 = f2bf(acc.x), h1 = f2bf(acc.y), h2 = f2bf(acc.z), h3 = f2bf(acc.w);
        unsigned short l0 = f2bf(acc.x - bf2f(h0));
        unsigned short l1 = f2bf(acc.y - bf2f(h1));
        unsigned short l2 = f2bf(acc.z - bf2f(h2));
        unsigned short l3 = f2bf(acc.w - bf2f(h3));
        uint2 hv2, lv2;
        hv2.x = (unsigned)h0 | ((unsigned)h1 << 16);
        hv2.y = (unsigned)h2 | ((unsigned)h3 << 16);
        lv2.x = (unsigned)l0 | ((unsigned)l1 << 16);
        lv2.y = (unsigned)l2 | ((unsigned)l3 << 16);
        *(uint2*)(Xh + r * XS + c4) = hv2;
        *(uint2*)(Xl + r * XS + c4) = lv2;
    }
    __syncthreads();

    // ---- MFMA phase: 4 waves x 16 rows, 8 n-tiles of 16, K=128 in 4 steps ----
    int lane = tid & 63, w = tid >> 6;
    int m16 = lane & 15, quad = lane >> 4;
    int rowA = w * 16 + m16;

    floatx4 acc[8];
    #pragma unroll
    for (int t = 0; t < 8; t++) acc[t] = (floatx4){0.f, 0.f, 0.f, 0.f};

    #pragma unroll
    for (int kp = 0; kp < 4; kp++) {
        bf16x8 ah = *(const bf16x8*)(Xh + rowA * XS + kp * 32 + quad * 8);
        bf16x8 al = *(const bf16x8*)(Xl + rowA * XS + kp * 32 + quad * 8);
        #pragma unroll
        for (int t = 0; t < 8; t++) {
            int ncol = t * 16 + m16;
            bf16x8 bh = *(const bf16x8*)(Wht + (size_t)ncol * DD + kp * 32 + quad * 8);
            bf16x8 bl = *(const bf16x8*)(Wlt + (size_t)ncol * DD + kp * 32 + quad * 8);
            acc[t] = __builtin_amdgcn_mfma_f32_16x16x32_bf16(ah, bh, acc[t], 0, 0, 0);
            acc[t] = __builtin_amdgcn_mfma_f32_16x16x32_bf16(ah, bl, acc[t], 0, 0, 0);
            acc[t] = __builtin_amdgcn_mfma_f32_16x16x32_bf16(al, bh, acc[t], 0, 0, 0);
        }
    }

    // ---- epilogue: bias, store C, BN partials ----
    float* redS = red;
    float* redQ = red + 4 * DD;
    #pragma unroll
    for (int t = 0; t < 8; t++) {
        int col = t * 16 + m16;
        float bv = bias[col];
        float s = 0.f, q = 0.f;
        #pragma unroll
        for (int rr = 0; rr < 4; rr++) {
            float v = acc[t][rr] + bv;
            C[(size_t)(n0 + w * 16 + quad * 4 + rr) * DD + col] = v;
            s += v; q += v * v;
        }
        s += __shfl_xor(s, 16); q += __shfl_xor(q, 16);
        s += __shfl_xor(s, 32); q += __shfl_xor(q, 32);
        if (lane < 16) { redS[w * DD + col] = s; redQ[w * DD + col] = q; }
    }
    __syncthreads();
    if (tid < DD) {
        float ss = 0.f, qq = 0.f;
        #pragma unroll
        for (int t = 0; t < 4; t++) {
            ss += redS[t * DD + tid];
            qq += redQ[t * DD + tid];
        }
        part[(size_t)tid * NBLK2 + blockIdx.x] = ss;
        part[(size_t)(DD + tid) * NBLK2 + blockIdx.x] = qq;
    }
}

// ---------------- reduce BN stats ----------------
__global__ void k_stats(const float* __restrict__ part,
                        float* __restrict__ mu, float* __restrict__ rsig) {
    int col = blockIdx.x;
    float s = 0.f, q = 0.f;
    for (int i = threadIdx.x; i < NBLK2; i += 256) {
        s += part[(size_t)col * NBLK2 + i];
        q += part[(size_t)(DD + col) * NBLK2 + i];
    }
    #pragma unroll
    for (int o = 32; o > 0; o >>= 1) {
        s += __shfl_down(s, o);
        q += __shfl_down(q, o);
    }
    __shared__ float sh[8];
    int lane = threadIdx.x & 63, w = threadIdx.x >> 6;
    if (lane == 0) { sh[w] = s; sh[4 + w] = q; }
    __syncthreads();
    if (threadIdx.x == 0) {
        float S = sh[0] + sh[1] + sh[2] + sh[3];
        float Q = sh[4] + sh[5] + sh[6] + sh[7];
        float m = S / (float)NN;
        float v = Q / (float)NN - m * m;
        mu[col] = m;
        rsig[col] = rsqrtf(v + EPS);
    }
}

// ---------------- last layer: BN + ReLU fused with graph-sum pooling ----------------
__global__ void k_bnpool(const float* __restrict__ A, const int* __restrict__ n2g,
                         const float* __restrict__ mu, const float* __restrict__ rsig,
                         const float* __restrict__ gamma, const float* __restrict__ beta,
                         float* __restrict__ gsum) {
    int j = threadIdx.x;
    int n0 = blockIdx.x * CHUNK;
    float m = mu[j], r = rsig[j], ga = gamma[j], be = beta[j];
    int cur = n2g[n0];
    float acc = 0.f;
    for (int i = 0; i < CHUNK; i++) {
        int n = n0 + i;
        int gg = n2g[n];
        if (gg != cur) {
            atomicAdd(&gsum[(size_t)cur * DD + j], acc);
            acc = 0.f;
            cur = gg;
        }
        float x = A[(size_t)n * DD + j];
        x = fmaxf(0.f, (x - m) * r * ga + be);
        acc += x;
    }
    atomicAdd(&gsum[(size_t)cur * DD + j], acc);
}

// ---------------- final MLP ----------------
__global__ void k_mlp(const float* __restrict__ gsum, const float* __restrict__ gcnt,
                      const float* __restrict__ W1, const float* __restrict__ b1,
                      const float* __restrict__ W2, const float* __restrict__ b2,
                      float* __restrict__ out) {
    __shared__ float gs[DD], hs[DD];
    int gid = blockIdx.x, j = threadIdx.x;
    float inv = 1.0f / fmaxf(gcnt[gid], 1.0f);
    gs[j] = gsum[(size_t)gid * DD + j] * inv;
    __syncthreads();
    float a = b1[j];
    for (int k = 0; k < DD; k++) a += gs[k] * W1[k * DD + j];
    hs[j] = fmaxf(a, 0.f);
    __syncthreads();
    float o = b2[j];
    for (int k = 0; k < DD; k++) o += hs[k] * W2[k * DD + j];
    out[(size_t)gid * DD + j] = o;
}

extern "C" void kernel_launch(void* const* d_in, const int* in_sizes, int n_in,
                              void* d_out, int out_size, void* d_ws, size_t ws_size,
                              hipStream_t stream) {
    const int*   nfeat = (const int*)d_in[0];
    const int*   efeat = (const int*)d_in[1];
    const int*   src   = (const int*)d_in[2];
    const int*   dst   = (const int*)d_in[3];
    const int*   n2g   = (const int*)d_in[4];
    const float* aemb  = (const float*)d_in[5];
    const float* eemb  = (const float*)d_in[6];   // [L][5][128]
    const float* Wl    = (const float*)d_in[7];   // [L][128][128]
    const float* bl    = (const float*)d_in[8];   // [L][128]
    const float* gam   = (const float*)d_in[9];
    const float* bet   = (const float*)d_in[10];
    const float* W1    = (const float*)d_in[11];
    const float* b1    = (const float*)d_in[12];
    const float* W2    = (const float*)d_in[13];
    const float* b2    = (const float*)d_in[14];
    float* out = (float*)d_out;

    float* ws   = (float*)d_ws;
    float* H0   = ws;                          // NN*DD
    float* H1   = H0 + (size_t)NN * DD;        // NN*DD
    float* rdeg = H1 + (size_t)NN * DD;        // NN
    float* gsum = rdeg + NN;                   // NG*DD
    float* gcnt = gsum + (size_t)NG * DD;      // NG
    float* mu   = gcnt + NG;                   // DD
    float* rsg  = mu + DD;                     // DD
    float* part = rsg + DD;                    // 2*DD*NBLK2 = 800000 floats
    unsigned short* Wht = (unsigned short*)(part + (size_t)2 * DD * NBLK2);  // NL*DD*DD
    unsigned short* Wlt = Wht + (size_t)NL * DD * DD;
    int* off  = (int*)(Wlt + (size_t)NL * DD * DD);   // NN+1
    int* cur  = off + NN + 1;                  // NN
    int* esrc = cur + NN;                      // NE
    int* eft  = esrc + NE;                     // NE
    // CSR-build scratch aliases part (dead before first k_fused)
    int* cnt  = (int*)part;                    // NN
    int* bsum = (int*)part + 300000;           // NB_SCAN
    int* bpre = (int*)part + 301000;           // NB_SCAN

    hipMemsetAsync(cnt, 0, (size_t)NN * sizeof(int), stream);
    hipMemsetAsync(gsum, 0, (size_t)(NG * DD + NG) * sizeof(float), stream);

    k_deg_int<<<(NE + 255) / 256, 256, 0, stream>>>(dst, cnt);
    k_cnt<<<(NN + 255) / 256, 256, 0, stream>>>(n2g, gcnt);
    k_scan1<<<NB_SCAN, 256, 0, stream>>>(cnt, bsum);
    k_scan2<<<1, 64, 0, stream>>>(bsum, bpre, off);
    k_scan3<<<NB_SCAN, 256, 0, stream>>>(cnt, bpre, off, cur);
    k_rdeg<<<(NN + 255) / 256, 256, 0, stream>>>(cnt, rdeg);
    k_bucket<<<(NE + 255) / 256, 256, 0, stream>>>(src, dst, efeat, cur, esrc, eft);
    k_wsplit<<<(NL * DD * DD + 255) / 256, 256, 0, stream>>>(Wl, Wht, Wlt);

    float* hcur = H0;   // holds h after each layer's GEMM
    for (int l = 0; l < NL; l++) {
        const float* base = (l == 0) ? aemb : hcur;
        float* hnext = (l == 0) ? H0 : ((hcur == H0) ? H1 : H0);
        const float* g_prev = (l == 0) ? gam : gam + (size_t)(l - 1) * DD;
        const float* b_prev = (l == 0) ? bet : bet + (size_t)(l - 1) * DD;
        k_fused<<<NBLK2, 256, 0, stream>>>(base, nfeat, (l == 0) ? 1 : 0,
                                           off, esrc, eft,
                                           eemb + (size_t)l * BOND_V * DD, rdeg,
                                           mu, rsg, g_prev, b_prev,
                                           Wht + (size_t)l * DD * DD,
                                           Wlt + (size_t)l * DD * DD,
                                           bl + (size_t)l * DD, hnext, part);
        k_stats<<<DD, 256, 0, stream>>>(part, mu, rsg);
        hcur = hnext;
    }
    k_bnpool<<<NN / CHUNK, DD, 0, stream>>>(hcur, n2g, mu, rsg,
                                            gam + (size_t)(NL - 1) * DD,
                                            bet + (size_t)(NL - 1) * DD, gsum);
    k_mlp<<<NG, DD, 0, stream>>>(gsum, gcnt, W1, b1, W2, b2, out);
}

// Round 4
// 1143.290 us; speedup vs baseline: 1.3277x; 1.3277x over previous
//
#include <hip/hip_runtime.h>
#include <hip/hip_bf16.h>
#include <cstddef>

#define NN 200000   // nodes
#define NE 400000   // edges
#define DD 128      // embed dim
#define NL 5        // layers
#define NG 1000     // graphs
#define BOND_V 5
#define BM 32             // rows per fused block
#define NBLK (NN / BM)    // 6250
#define CAPE 256          // LDS edge-stage capacity per block (avg 64, +24 sigma safe)
#define CHUNK 200         // pool chunk
#define NB_SCAN 200
#define CH 1000
#define EPS 1e-5f
#define XS 136            // LDS bf16 row stride (shorts)

typedef __bf16 bf16x8 __attribute__((ext_vector_type(8)));
typedef float floatx4 __attribute__((ext_vector_type(4)));

__device__ __forceinline__ unsigned short f2bf(float f) {
    unsigned int u = __float_as_uint(f);
    u = (u + 0x7fffu + ((u >> 16) & 1u)) >> 16;
    return (unsigned short)u;
}
__device__ __forceinline__ float bf2f(unsigned short s) {
    return __uint_as_float(((unsigned int)s) << 16);
}

// ---------------- degree / counts ----------------
__global__ void k_deg_int(const int* __restrict__ dst, int* __restrict__ cnt) {
    int e = blockIdx.x * blockDim.x + threadIdx.x;
    if (e < NE) atomicAdd(&cnt[dst[e]], 1);
}

__global__ void k_cnt(const int* __restrict__ n2g, float* __restrict__ gcnt) {
    int n = blockIdx.x * blockDim.x + threadIdx.x;
    if (n < NN) atomicAdd(&gcnt[n2g[n]], 1.0f);
}

__global__ void k_rdeg(const int* __restrict__ cnt, float* __restrict__ rdeg) {
    int n = blockIdx.x * blockDim.x + threadIdx.x;
    if (n < NN) rdeg[n] = 1.0f / (float)(cnt[n] + 1);
}

// ---------------- CSR build ----------------
__global__ void k_scan1(const int* __restrict__ cnt, int* __restrict__ bsum) {
    __shared__ int sh[256];
    int b = blockIdx.x, t = threadIdx.x;
    int s = 0;
    if (t < CH / 4) {
        int base = b * CH + t * 4;
        s = cnt[base] + cnt[base + 1] + cnt[base + 2] + cnt[base + 3];
    }
    sh[t] = s;
    __syncthreads();
    if (t == 0) {
        int tot = 0;
        for (int i = 0; i < CH / 4; i++) tot += sh[i];
        bsum[b] = tot;
    }
}

__global__ void k_scan2(const int* __restrict__ bsum, int* __restrict__ bpre,
                        int* __restrict__ off) {
    if (threadIdx.x == 0) {
        int run = 0;
        for (int i = 0; i < NB_SCAN; i++) { bpre[i] = run; run += bsum[i]; }
        off[NN] = NE;
    }
}

__global__ void k_scan3(const int* __restrict__ cnt, const int* __restrict__ bpre,
                        int* __restrict__ off, int* __restrict__ cur) {
    __shared__ int sh[256];
    int b = blockIdx.x, t = threadIdx.x;
    int base = b * CH + t * 4;
    int c0 = 0, c1 = 0, c2 = 0, c3 = 0, s = 0;
    if (t < CH / 4) {
        c0 = cnt[base]; c1 = cnt[base + 1]; c2 = cnt[base + 2]; c3 = cnt[base + 3];
        s = c0 + c1 + c2 + c3;
    }
    sh[t] = s;
    __syncthreads();
    if (t == 0) {
        int run = bpre[b];
        for (int i = 0; i < CH / 4; i++) { int v = sh[i]; sh[i] = run; run += v; }
    }
    __syncthreads();
    if (t < CH / 4) {
        int run = sh[t];
        off[base] = run; cur[base] = run; run += c0;
        off[base + 1] = run; cur[base + 1] = run; run += c1;
        off[base + 2] = run; cur[base + 2] = run; run += c2;
        off[base + 3] = run; cur[base + 3] = run;
    }
}

__global__ void k_bucket(const int* __restrict__ src, const int* __restrict__ dst,
                         const int* __restrict__ efeat, int* __restrict__ cur,
                         int* __restrict__ esrc, int* __restrict__ eft) {
    int e = blockIdx.x * blockDim.x + threadIdx.x;
    if (e < NE) {
        int p = atomicAdd(&cur[dst[e]], 1);
        esrc[p] = src[e];
        eft[p] = efeat[e];
    }
}

// ---------------- W split: fp32 [l][k][n] -> bf16 hi/lo transposed [l][n][k] ----------------
__global__ void k_wsplit(const float* __restrict__ W, unsigned short* __restrict__ Wht,
                         unsigned short* __restrict__ Wlt) {
    int idx = blockIdx.x * 256 + threadIdx.x;
    if (idx >= NL * DD * DD) return;
    int l = idx / (DD * DD), rem = idx % (DD * DD);
    int k = rem / DD, n = rem % DD;
    float v = W[idx];
    unsigned short hb = f2bf(v);
    unsigned short lb = f2bf(v - bf2f(hb));
    size_t o = (size_t)l * DD * DD + (size_t)n * DD + k;
    Wht[o] = hb; Wlt[o] = lb;
}

// ---------------- fused BN+ReLU helper ----------------
__device__ __forceinline__ float4 bnrelu4(float4 x, float4 m, float4 r, float4 g, float4 b) {
    float4 o;
    o.x = fmaxf(0.f, (x.x - m.x) * r.x * g.x + b.x);
    o.y = fmaxf(0.f, (x.y - m.y) * r.y * g.y + b.y);
    o.z = fmaxf(0.f, (x.z - m.z) * r.z * g.z + b.z);
    o.w = fmaxf(0.f, (x.w - m.w) * r.w * g.w + b.w);
    return o;
}

// ---------------- fused layer: agg (LDS-staged CSR, 2-wide edge loop, prev BN/ReLU)
// -> LDS bf16 hi/lo -> split MFMA -> bias -> C, BN-stat partials ----------------
__global__ __launch_bounds__(256)
void k_fused(const float* __restrict__ base, const int* __restrict__ nfeat, int first,
             const int* __restrict__ off, const int* __restrict__ esrc,
             const int* __restrict__ eft, const float* __restrict__ eemb,
             const float* __restrict__ rdeg,
             const float* __restrict__ mu, const float* __restrict__ rsig,
             const float* __restrict__ gamma, const float* __restrict__ beta,
             const unsigned short* __restrict__ Wht, const unsigned short* __restrict__ Wlt,
             const float* __restrict__ bias,
             float* __restrict__ C, float* __restrict__ part) {
    __shared__ unsigned short Xh[BM * XS];   // 8704 B
    __shared__ unsigned short Xl[BM * XS];   // 8704 B
    __shared__ float eS[BOND_V * DD];        // 2560 B
    __shared__ float red[4 * DD];            // 2048 B
    __shared__ int esL[CAPE], efL[CAPE];     // 2048 B
    __shared__ int offL[BM + 1];

    int tid = threadIdx.x;
    int n0 = blockIdx.x * BM;
    if (tid < BOND_V * DD / 4)
        *(float4*)(eS + tid * 4) = *(const float4*)(eemb + tid * 4);
    if (tid <= BM) offL[tid] = off[n0 + tid];
    int e_beg = off[n0], e_end = off[n0 + BM];
    for (int e = e_beg + tid; e < e_end; e += 256) {
        int idx = e - e_beg;
        if (idx < CAPE) { esL[idx] = esrc[e]; efL[idx] = eft[e]; }
    }

    int lane32 = tid & 31, grp = tid >> 5;
    int c4 = lane32 << 2;
    float4 m4, r4, g4, b4;
    if (!first) {
        m4 = *(const float4*)(mu + c4);
        r4 = *(const float4*)(rsig + c4);
        g4 = *(const float4*)(gamma + c4);
        b4 = *(const float4*)(beta + c4);
    }
    __syncthreads();

    bool lds_ok = (e_end - e_beg) <= CAPE;

    // ---- aggregation: 8 groups x 4 rows ----
    for (int i = 0; i < 4; i++) {
        int r = grp * 4 + i;
        int n = n0 + r;
        int rown = first ? nfeat[n] : n;
        float4 acc = *(const float4*)(base + (size_t)rown * DD + c4);
        if (!first) acc = bnrelu4(acc, m4, r4, g4, b4);
        int e0 = offL[r], e1 = offL[r + 1];
        int k = e0;
        if (lds_ok) {
            for (; k + 1 < e1; k += 2) {
                int i0 = k - e_beg;
                int s0 = esL[i0], f0 = efL[i0];
                int s1 = esL[i0 + 1], f1 = efL[i0 + 1];
                if (first) { s0 = nfeat[s0]; s1 = nfeat[s1]; }
                float4 h0 = *(const float4*)(base + (size_t)s0 * DD + c4);
                float4 h1 = *(const float4*)(base + (size_t)s1 * DD + c4);
                if (!first) { h0 = bnrelu4(h0, m4, r4, g4, b4); h1 = bnrelu4(h1, m4, r4, g4, b4); }
                float4 ev0 = *(const float4*)(eS + f0 * DD + c4);
                float4 ev1 = *(const float4*)(eS + f1 * DD + c4);
                acc.x += h0.x + ev0.x + h1.x + ev1.x;
                acc.y += h0.y + ev0.y + h1.y + ev1.y;
                acc.z += h0.z + ev0.z + h1.z + ev1.z;
                acc.w += h0.w + ev0.w + h1.w + ev1.w;
            }
            if (k < e1) {
                int i0 = k - e_beg;
                int s0 = esL[i0], f0 = efL[i0];
                if (first) s0 = nfeat[s0];
                float4 h0 = *(const float4*)(base + (size_t)s0 * DD + c4);
                if (!first) h0 = bnrelu4(h0, m4, r4, g4, b4);
                float4 ev0 = *(const float4*)(eS + f0 * DD + c4);
                acc.x += h0.x + ev0.x; acc.y += h0.y + ev0.y;
                acc.z += h0.z + ev0.z; acc.w += h0.w + ev0.w;
            }
        } else {
            for (; k < e1; k++) {
                int s0 = esrc[k], f0 = eft[k];
                if (first) s0 = nfeat[s0];
                float4 h0 = *(const float4*)(base + (size_t)s0 * DD + c4);
                if (!first) h0 = bnrelu4(h0, m4, r4, g4, b4);
                float4 ev0 = *(const float4*)(eS + f0 * DD + c4);
                acc.x += h0.x + ev0.x; acc.y += h0.y + ev0.y;
                acc.z += h0.z + ev0.z; acc.w += h0.w + ev0.w;
            }
        }
        float rd = rdeg[n];
        acc.x *= rd; acc.y *= rd; acc.z *= rd; acc.w *= rd;
        unsigned short h0 = f2bf(acc.x), h1 = f2bf(acc.y), h2 = f2bf(acc.z), h3 = f2bf(acc.w);
        unsigned short l0 = f2bf(acc.x - bf2f(h0));
        unsigned short l1 = f2bf(acc.y - bf2f(h1));
        unsigned short l2 = f2bf(acc.z - bf2f(h2));
        unsigned short l3 = f2bf(acc.w - bf2f(h3));
        uint2 hv2, lv2;
        hv2.x = (unsigned)h0 | ((unsigned)h1 << 16);
        hv2.y = (unsigned)h2 | ((unsigned)h3 << 16);
        lv2.x = (unsigned)l0 | ((unsigned)l1 << 16);
        lv2.y = (unsigned)l2 | ((unsigned)l3 << 16);
        *(uint2*)(Xh + r * XS + c4) = hv2;
        *(uint2*)(Xl + r * XS + c4) = lv2;
    }
    __syncthreads();

    // ---- MFMA: 4 waves; wave w -> row-tile (w&1), col-tiles (w>>1)*4 .. +3 ----
    int lane = tid & 63, w = tid >> 6;
    int m16 = lane & 15, quad = lane >> 4;
    int rowTile = w & 1;
    int colBase = (w >> 1) << 6;
    int rowA = rowTile * 16 + m16;

    floatx4 acc4[4];
    #pragma unroll
    for (int t = 0; t < 4; t++) acc4[t] = (floatx4){0.f, 0.f, 0.f, 0.f};

    #pragma unroll
    for (int kp = 0; kp < 4; kp++) {
        bf16x8 ah = *(const bf16x8*)(Xh + rowA * XS + kp * 32 + quad * 8);
        bf16x8 al = *(const bf16x8*)(Xl + rowA * XS + kp * 32 + quad * 8);
        #pragma unroll
        for (int t = 0; t < 4; t++) {
            int ncol = colBase + t * 16 + m16;
            bf16x8 bh = *(const bf16x8*)(Wht + (size_t)ncol * DD + kp * 32 + quad * 8);
            bf16x8 bl = *(const bf16x8*)(Wlt + (size_t)ncol * DD + kp * 32 + quad * 8);
            acc4[t] = __builtin_amdgcn_mfma_f32_16x16x32_bf16(ah, bh, acc4[t], 0, 0, 0);
            acc4[t] = __builtin_amdgcn_mfma_f32_16x16x32_bf16(ah, bl, acc4[t], 0, 0, 0);
            acc4[t] = __builtin_amdgcn_mfma_f32_16x16x32_bf16(al, bh, acc4[t], 0, 0, 0);
        }
    }

    // ---- epilogue: bias, store C, BN partials ----
    float* redS = red;
    float* redQ = red + 2 * DD;
    #pragma unroll
    for (int t = 0; t < 4; t++) {
        int col = colBase + t * 16 + m16;
        float bv = bias[col];
        float s = 0.f, q = 0.f;
        #pragma unroll
        for (int rr = 0; rr < 4; rr++) {
            float v = acc4[t][rr] + bv;
            C[(size_t)(n0 + rowTile * 16 + quad * 4 + rr) * DD + col] = v;
            s += v; q += v * v;
        }
        s += __shfl_xor(s, 16); q += __shfl_xor(q, 16);
        s += __shfl_xor(s, 32); q += __shfl_xor(q, 32);
        if (lane < 16) { redS[rowTile * DD + col] = s; redQ[rowTile * DD + col] = q; }
    }
    __syncthreads();
    if (tid < DD) {
        float ss = redS[tid] + redS[DD + tid];
        float qq = redQ[tid] + redQ[DD + tid];
        part[(size_t)tid * NBLK + blockIdx.x] = ss;
        part[(size_t)(DD + tid) * NBLK + blockIdx.x] = qq;
    }
}

// ---------------- reduce BN stats ----------------
__global__ void k_stats(const float* __restrict__ part,
                        float* __restrict__ mu, float* __restrict__ rsig) {
    int col = blockIdx.x;
    float s = 0.f, q = 0.f;
    for (int i = threadIdx.x; i < NBLK; i += 256) {
        s += part[(size_t)col * NBLK + i];
        q += part[(size_t)(DD + col) * NBLK + i];
    }
    #pragma unroll
    for (int o = 32; o > 0; o >>= 1) {
        s += __shfl_down(s, o);
        q += __shfl_down(q, o);
    }
    __shared__ float sh[8];
    int lane = threadIdx.x & 63, w = threadIdx.x >> 6;
    if (lane == 0) { sh[w] = s; sh[4 + w] = q; }
    __syncthreads();
    if (threadIdx.x == 0) {
        float S = sh[0] + sh[1] + sh[2] + sh[3];
        float Q = sh[4] + sh[5] + sh[6] + sh[7];
        float m = S / (float)NN;
        float v = Q / (float)NN - m * m;
        mu[col] = m;
        rsig[col] = rsqrtf(v + EPS);
    }
}

// ---------------- last layer: BN + ReLU fused with graph-sum pooling ----------------
__global__ void k_bnpool(const float* __restrict__ A, const int* __restrict__ n2g,
                         const float* __restrict__ mu, const float* __restrict__ rsig,
                         const float* __restrict__ gamma, const float* __restrict__ beta,
                         float* __restrict__ gsum) {
    int j = threadIdx.x;
    int n0 = blockIdx.x * CHUNK;
    float m = mu[j], r = rsig[j], ga = gamma[j], be = beta[j];
    int cur = n2g[n0];
    float acc = 0.f;
    for (int i = 0; i < CHUNK; i++) {
        int n = n0 + i;
        int gg = n2g[n];
        if (gg != cur) {
            atomicAdd(&gsum[(size_t)cur * DD + j], acc);
            acc = 0.f;
            cur = gg;
        }
        float x = A[(size_t)n * DD + j];
        x = fmaxf(0.f, (x - m) * r * ga + be);
        acc += x;
    }
    atomicAdd(&gsum[(size_t)cur * DD + j], acc);
}

// ---------------- final MLP ----------------
__global__ void k_mlp(const float* __restrict__ gsum, const float* __restrict__ gcnt,
                      const float* __restrict__ W1, const float* __restrict__ b1,
                      const float* __restrict__ W2, const float* __restrict__ b2,
                      float* __restrict__ out) {
    __shared__ float gs[DD], hs[DD];
    int gid = blockIdx.x, j = threadIdx.x;
    float inv = 1.0f / fmaxf(gcnt[gid], 1.0f);
    gs[j] = gsum[(size_t)gid * DD + j] * inv;
    __syncthreads();
    float a = b1[j];
    for (int k = 0; k < DD; k++) a += gs[k] * W1[k * DD + j];
    hs[j] = fmaxf(a, 0.f);
    __syncthreads();
    float o = b2[j];
    for (int k = 0; k < DD; k++) o += hs[k] * W2[k * DD + j];
    out[(size_t)gid * DD + j] = o;
}

extern "C" void kernel_launch(void* const* d_in, const int* in_sizes, int n_in,
                              void* d_out, int out_size, void* d_ws, size_t ws_size,
                              hipStream_t stream) {
    const int*   nfeat = (const int*)d_in[0];
    const int*   efeat = (const int*)d_in[1];
    const int*   src   = (const int*)d_in[2];
    const int*   dst   = (const int*)d_in[3];
    const int*   n2g   = (const int*)d_in[4];
    const float* aemb  = (const float*)d_in[5];
    const float* eemb  = (const float*)d_in[6];   // [L][5][128]
    const float* Wl    = (const float*)d_in[7];   // [L][128][128]
    const float* bl    = (const float*)d_in[8];   // [L][128]
    const float* gam   = (const float*)d_in[9];
    const float* bet   = (const float*)d_in[10];
    const float* W1    = (const float*)d_in[11];
    const float* b1    = (const float*)d_in[12];
    const float* W2    = (const float*)d_in[13];
    const float* b2    = (const float*)d_in[14];
    float* out = (float*)d_out;

    float* ws   = (float*)d_ws;
    float* H0   = ws;                          // NN*DD
    float* H1   = H0 + (size_t)NN * DD;        // NN*DD
    float* rdeg = H1 + (size_t)NN * DD;        // NN
    float* gsum = rdeg + NN;                   // NG*DD
    float* gcnt = gsum + (size_t)NG * DD;      // NG
    float* mu   = gcnt + NG;                   // DD
    float* rsg  = mu + DD;                     // DD
    float* part = rsg + DD;                    // 2*DD*NBLK = 1.6M floats
    unsigned short* Wht = (unsigned short*)(part + (size_t)2 * DD * NBLK);  // NL*DD*DD
    unsigned short* Wlt = Wht + (size_t)NL * DD * DD;
    int* off  = (int*)(Wlt + (size_t)NL * DD * DD);   // NN+1
    int* cur  = off + NN + 1;                  // NN
    int* esrc = cur + NN;                      // NE
    int* eft  = esrc + NE;                     // NE
    // CSR-build scratch aliases part (dead before first k_fused)
    int* cnt  = (int*)part;                    // NN
    int* bsum = (int*)part + 300000;           // NB_SCAN
    int* bpre = (int*)part + 301000;           // NB_SCAN

    hipMemsetAsync(cnt, 0, (size_t)NN * sizeof(int), stream);
    hipMemsetAsync(gsum, 0, (size_t)(NG * DD + NG) * sizeof(float), stream);

    k_deg_int<<<(NE + 255) / 256, 256, 0, stream>>>(dst, cnt);
    k_cnt<<<(NN + 255) / 256, 256, 0, stream>>>(n2g, gcnt);
    k_scan1<<<NB_SCAN, 256, 0, stream>>>(cnt, bsum);
    k_scan2<<<1, 64, 0, stream>>>(bsum, bpre, off);
    k_scan3<<<NB_SCAN, 256, 0, stream>>>(cnt, bpre, off, cur);
    k_rdeg<<<(NN + 255) / 256, 256, 0, stream>>>(cnt, rdeg);
    k_bucket<<<(NE + 255) / 256, 256, 0, stream>>>(src, dst, efeat, cur, esrc, eft);
    k_wsplit<<<(NL * DD * DD + 255) / 256, 256, 0, stream>>>(Wl, Wht, Wlt);

    float* hcur = H0;
    for (int l = 0; l < NL; l++) {
        const float* base = (l == 0) ? aemb : hcur;
        float* hnext = (l == 0) ? H0 : ((hcur == H0) ? H1 : H0);
        const float* g_prev = (l == 0) ? gam : gam + (size_t)(l - 1) * DD;
        const float* b_prev = (l == 0) ? bet : bet + (size_t)(l - 1) * DD;
        k_fused<<<NBLK, 256, 0, stream>>>(base, nfeat, (l == 0) ? 1 : 0,
                                          off, esrc, eft,
                                          eemb + (size_t)l * BOND_V * DD, rdeg,
                                          mu, rsg, g_prev, b_prev,
                                          Wht + (size_t)l * DD * DD,
                                          Wlt + (size_t)l * DD * DD,
                                          bl + (size_t)l * DD, hnext, part);
        k_stats<<<DD, 256, 0, stream>>>(part, mu, rsg);
        hcur = hnext;
    }
    k_bnpool<<<NN / CHUNK, DD, 0, stream>>>(hcur, n2g, mu, rsg,
                                            gam + (size_t)(NL - 1) * DD,
                                            bet + (size_t)(NL - 1) * DD, gsum);
    k_mlp<<<NG, DD, 0, stream>>>(gsum, gcnt, W1, b1, W2, b2, out);
}